// Round 8
// baseline (43.284 us; speedup 1.0000x reference)
//
#include <hip/hip_runtime.h>
#include <math.h>
#include <limits.h>
#include <stdint.h>

#define T_LEN 6000
#define B_ROWS 4096
#define PICK_WIN 20
#define BETA 25.0f
#define SCALE_L1 2097152.0f      // 2^21: row L1 sums ~7e3 -> <2^34 scaled; x4096 < 2^46
#define SCALE_PK 67108864.0f     // 2^26: pick diffs <=40 -> <2^32 scaled
#define GRP_STRIDE 256           // one counter record per 256B line (channel-spread)

typedef float f4 __attribute__((ext_vector_type(4)));

// ---------------------------------------------------------------------------
// Single fused kernel. 1 row per 128-thread block (grid 4096). 1500 float4/row:
// threads 0..91 own 12 slots, rest 11 (slot 11 clamped to the row's last f4 —
// same line thread 91 loads, so the dup is coalesced/free). 24 loads/thread,
// pair-interleaved asm; consume pairs 0..5 at vmcnt(12), 6..11 at vmcnt(0).
// Tail: distributed fixed-point atomic tree (64 group lines + 1 top line).
// r3/r4 lesson: same-line RMW ~10ns serialized -> 12k same-line RMWs = +123us.
// Here: <=192 RMWs per line spread over ~33us -> negligible queuing, and the
// separate finalize kernel + dispatch gap (~4-5us serial) disappears.
// Integer adds are associative -> deterministic (validated bit-exact in r4).
// ---------------------------------------------------------------------------
__global__ __launch_bounds__(128) void fused_loss(const float* __restrict__ pred,
                                                  const float* __restrict__ target,
                                                  char* __restrict__ cnts,
                                                  float* __restrict__ out) {
    const int row  = blockIdx.x;
    const int tid  = threadIdx.x;
    const int wave = tid >> 6;
    const int lane = tid & 63;

    const uint64_t pb = (uint64_t)(pred   + (size_t)row * T_LEN);
    const uint64_t tb = (uint64_t)(target + (size_t)row * T_LEN);

    // 1500 = 11*128 + 92: threads 0..91 have a 12th slot.
    const bool has12 = (tid < (T_LEN / 4 - 11 * 128));   // tid < 92
    uint32_t va[12];
    #pragma unroll
    for (int k = 0; k < 11; ++k) va[k] = (uint32_t)(tid + k * 128) * 16u;
    va[11] = has12 ? (uint32_t)(tid + 11 * 128) * 16u
                   : (uint32_t)((T_LEN / 4 - 1) * 16);

    f4 p0, p1, p2, p3, p4, p5, p6, p7, p8, p9, p10, p11;
    f4 t0, t1, t2, t3, t4, t5, t6, t7, t8, t9, t10, t11;

    // pairs 0..5 (issue order p_k,t_k -> vmcnt counts in order)
    asm volatile(
        "global_load_dwordx4 %0,  %12, %18\n\t"
        "global_load_dwordx4 %6,  %12, %19\n\t"
        "global_load_dwordx4 %1,  %13, %18\n\t"
        "global_load_dwordx4 %7,  %13, %19\n\t"
        "global_load_dwordx4 %2,  %14, %18\n\t"
        "global_load_dwordx4 %8,  %14, %19\n\t"
        "global_load_dwordx4 %3,  %15, %18\n\t"
        "global_load_dwordx4 %9,  %15, %19\n\t"
        "global_load_dwordx4 %4,  %16, %18\n\t"
        "global_load_dwordx4 %10, %16, %19\n\t"
        "global_load_dwordx4 %5,  %17, %18\n\t"
        "global_load_dwordx4 %11, %17, %19"
        : "=&v"(p0), "=&v"(p1), "=&v"(p2), "=&v"(p3), "=&v"(p4), "=&v"(p5),
          "=&v"(t0), "=&v"(t1), "=&v"(t2), "=&v"(t3), "=&v"(t4), "=&v"(t5)
        : "v"(va[0]), "v"(va[1]), "v"(va[2]), "v"(va[3]), "v"(va[4]), "v"(va[5]),
          "s"(pb), "s"(tb));
    // pairs 6..11
    asm volatile(
        "global_load_dwordx4 %0,  %12, %18\n\t"
        "global_load_dwordx4 %6,  %12, %19\n\t"
        "global_load_dwordx4 %1,  %13, %18\n\t"
        "global_load_dwordx4 %7,  %13, %19\n\t"
        "global_load_dwordx4 %2,  %14, %18\n\t"
        "global_load_dwordx4 %8,  %14, %19\n\t"
        "global_load_dwordx4 %3,  %15, %18\n\t"
        "global_load_dwordx4 %9,  %15, %19\n\t"
        "global_load_dwordx4 %4,  %16, %18\n\t"
        "global_load_dwordx4 %10, %16, %19\n\t"
        "global_load_dwordx4 %5,  %17, %18\n\t"
        "global_load_dwordx4 %11, %17, %19"
        : "=&v"(p6), "=&v"(p7), "=&v"(p8), "=&v"(p9), "=&v"(p10), "=&v"(p11),
          "=&v"(t6), "=&v"(t7), "=&v"(t8), "=&v"(t9), "=&v"(t10), "=&v"(t11)
        : "v"(va[6]), "v"(va[7]), "v"(va[8]), "v"(va[9]), "v"(va[10]), "v"(va[11]),
          "s"(pb), "s"(tb));

    float sum   = 0.0f;
    float bestv = -1.0f;            // |t| >= 0, always beaten
    int   besti = INT_MAX;

    // Indices strictly increase within a thread -> '>' keeps first occurrence.
#define CONSUME(PP, TT, K)                                                     \
    do {                                                                       \
        const int base = (tid + (K) * 128) * 4;                                \
        sum += fabsf(PP.x - TT.x) + fabsf(PP.y - TT.y) +                       \
               fabsf(PP.z - TT.z) + fabsf(PP.w - TT.w);                        \
        float a_;                                                              \
        a_ = fabsf(TT.x); if (a_ > bestv) { bestv = a_; besti = base;     }    \
        a_ = fabsf(TT.y); if (a_ > bestv) { bestv = a_; besti = base + 1; }    \
        a_ = fabsf(TT.z); if (a_ > bestv) { bestv = a_; besti = base + 2; }    \
        a_ = fabsf(TT.w); if (a_ > bestv) { bestv = a_; besti = base + 3; }    \
    } while (0)

    asm volatile("s_waitcnt vmcnt(12)" ::: "memory");
    __builtin_amdgcn_sched_barrier(0);
    CONSUME(p0, t0, 0);
    CONSUME(p1, t1, 1);
    CONSUME(p2, t2, 2);
    CONSUME(p3, t3, 3);
    CONSUME(p4, t4, 4);
    CONSUME(p5, t5, 5);

    asm volatile("s_waitcnt vmcnt(0)" ::: "memory");
    __builtin_amdgcn_sched_barrier(0);
    CONSUME(p6,  t6,  6);
    CONSUME(p7,  t7,  7);
    CONSUME(p8,  t8,  8);
    CONSUME(p9,  t9,  9);
    CONSUME(p10, t10, 10);
    if (has12) CONSUME(p11, t11, 11);
#undef CONSUME

    // ---- wave reduce: sum + argmax with tie -> min index
    #pragma unroll
    for (int o = 32; o > 0; o >>= 1) {
        sum += __shfl_xor(sum, o);
        const float ov = __shfl_xor(bestv, o);
        const int   oi = __shfl_xor(besti, o);
        if (ov > bestv || (ov == bestv && oi < besti)) { bestv = ov; besti = oi; }
    }

    __shared__ float s_sum[2];
    __shared__ float s_val[2];
    __shared__ int   s_idx[2];
    if (lane == 0) { s_sum[wave] = sum; s_val[wave] = bestv; s_idx[wave] = besti; }
    __syncthreads();

    // ---- wave 0: combine 2 partials, then the <=40-wide soft-argmax pick
    if (tid < 64) {
        float bs = s_sum[0] + s_sum[1];
        float bv = s_val[0];
        int   bi = s_idx[0];
        if (s_val[1] > bv || (s_val[1] == bv && s_idx[1] < bi)) {
            bv = s_val[1]; bi = s_idx[1];
        }

        const int c   = bi;
        const int s   = max(0, c - PICK_WIN);
        const int e   = min(T_LEN, c + PICK_WIN);
        const int len = e - s;

        float ap = -INFINITY, at = -INFINITY;
        const float posf = (float)(s + tid);
        if (tid < len) {
            const size_t idx = (size_t)row * T_LEN + s + tid;
            ap = BETA * fabsf(pred[idx]);     // L2-hot: just streamed
            at = BETA * fabsf(target[idx]);
        }

        float mp = ap, mt = at;
        #pragma unroll
        for (int o = 32; o > 0; o >>= 1) {
            mp = fmaxf(mp, __shfl_xor(mp, o));
            mt = fmaxf(mt, __shfl_xor(mt, o));
        }

        float wp = 0.0f, wt = 0.0f, wpp = 0.0f, wtp = 0.0f;
        if (tid < len) {
            wp  = expf(ap - mp);
            wt  = expf(at - mt);
            wpp = wp * posf;
            wtp = wt * posf;
        }
        #pragma unroll
        for (int o = 32; o > 0; o >>= 1) {
            wp  += __shfl_xor(wp,  o);
            wt  += __shfl_xor(wt,  o);
            wpp += __shfl_xor(wpp, o);
            wtp += __shfl_xor(wtp, o);
        }

        // ---- distributed fixed-point reduction tree (tid 0 only)
        if (tid == 0) {
            const float pickv = fabsf(wpp / wp - wtp / wt);
            const unsigned long long i1 =
                (unsigned long long)llrintf(bs * SCALE_L1);
            const unsigned long long i2 =
                (unsigned long long)llrintf(pickv * SCALE_PK);

            // group record: [u64 l1][u64 pick][u32 cnt] at (row/64)*256
            unsigned long long* gl1 =
                (unsigned long long*)(cnts + (size_t)(row >> 6) * GRP_STRIDE);
            unsigned long long* gpk  = gl1 + 1;
            unsigned*           gcnt = (unsigned*)(gl1 + 2);

            unsigned long long r1 = atomicAdd(gl1, i1);
            unsigned long long r2 = atomicAdd(gpk, i2);
            // Consuming the returns forces s_waitcnt on both RMW ACKs ->
            // value-adds are committed at the coherence point before the
            // counter bump below can be observed.
            asm volatile("" :: "v"(r1), "v"(r2) : "memory");

            const unsigned old = atomicAdd(gcnt, 1u);
            if (old == 63u) {                       // last of this group
                const unsigned long long g1 = atomicAdd(gl1, 0ull);
                const unsigned long long g2 = atomicAdd(gpk, 0ull);

                unsigned long long* tl1 =
                    (unsigned long long*)(cnts + (size_t)64 * GRP_STRIDE);
                unsigned long long* tpk  = tl1 + 1;
                unsigned*           tcnt = (unsigned*)(tl1 + 2);

                unsigned long long q1 = atomicAdd(tl1, g1);
                unsigned long long q2 = atomicAdd(tpk, g2);
                asm volatile("" :: "v"(q1), "v"(q2) : "memory");

                const unsigned told = atomicAdd(tcnt, 1u);
                if (told == 63u) {                  // last group overall
                    const unsigned long long s1 = atomicAdd(tl1, 0ull);
                    const unsigned long long s2 = atomicAdd(tpk, 0ull);
                    const double loss = ((double)s1 / (double)SCALE_L1) /
                                        ((double)B_ROWS * (double)T_LEN);
                    const double pick = (((double)s2 / (double)SCALE_PK) /
                                         (double)B_ROWS) / (double)T_LEN;
                    out[0] = (float)(loss + 0.1 * pick);
                }
            }
        }
    }
}

extern "C" void kernel_launch(void* const* d_in, const int* in_sizes, int n_in,
                              void* d_out, int out_size, void* d_ws, size_t ws_size,
                              hipStream_t stream) {
    const float* pred   = (const float*)d_in[0];
    const float* target = (const float*)d_in[1];
    float* out = (float*)d_out;

    // workspace: 65 records (64 groups + 1 top), 256B-strided
    char* cnts = (char*)d_ws;
    hipMemsetAsync(cnts, 0, 65 * GRP_STRIDE, stream);   // graph memset node

    fused_loss<<<B_ROWS, 128, 0, stream>>>(pred, target, cnts, out);
}

// Round 9
// 37.279 us; speedup vs baseline: 1.1611x; 1.1611x over previous
//
#include <hip/hip_runtime.h>
#include <math.h>
#include <limits.h>
#include <stdint.h>

#define T_LEN 6000
#define B_ROWS 4096
#define PICK_WIN 20
#define BETA 25.0f

typedef float f4 __attribute__((ext_vector_type(4)));

// ---------------------------------------------------------------------------
// K1: 2 rows per block (grid 2048). Per row: L1 sum + first-index
// argmax(|target|) + fused windowed soft-argmax pick.
// Loads: both rows' 12 dwordx4 clusters issued back-to-back (24 in flight);
// row0 consumed at vmcnt(12) while row1's loads still fly; row1 at vmcnt(0).
// Tail: interleaved wave reduce for both rows, one barrier, wave0 does row0's
// pick while wave1 does row1's (concurrent).
// NO global atomics: rounds 3/4/8 all showed any same-line RMW finalization
// (flat or 2-level tree) costs 3-130us more than the 2-kernel structure.
// This exact kernel measured 37.68us (round 6) — best of 8 rounds.
// ---------------------------------------------------------------------------
__global__ __launch_bounds__(256) void row_pass1(const float* __restrict__ pred,
                                                 const float* __restrict__ target,
                                                 float* __restrict__ row_l1,
                                                 float* __restrict__ row_pick) {
    const int row0 = blockIdx.x * 2;
    const int row1 = row0 + 1;
    const int tid  = threadIdx.x;
    const int wave = tid >> 6;
    const int lane = tid & 63;

    const uint64_t pb0 = (uint64_t)(pred   + (size_t)row0 * T_LEN);
    const uint64_t tb0 = (uint64_t)(target + (size_t)row0 * T_LEN);
    const uint64_t pb1 = (uint64_t)(pred   + (size_t)row1 * T_LEN);
    const uint64_t tb1 = (uint64_t)(target + (size_t)row1 * T_LEN);

    const bool has6 = (tid < (T_LEN / 4 - 5 * 256));   // tid < 220
    const uint32_t v0 = (uint32_t)tid * 16u;
    const uint32_t v1 = v0 + 1u * 4096u;
    const uint32_t v2 = v0 + 2u * 4096u;
    const uint32_t v3 = v0 + 3u * 4096u;
    const uint32_t v4 = v0 + 4u * 4096u;
    const uint32_t v5 = has6 ? (v0 + 5u * 4096u) : (uint32_t)((T_LEN / 4 - 1) * 16);

    f4 a0, a1, a2, a3, a4, a5, b0, b1, b2, b3, b4, b5;   // row0 pred/target
    f4 c0, c1, c2, c3, c4, c5, d0, d1, d2, d3, d4, d5;   // row1 pred/target
    asm volatile(
        "global_load_dwordx4 %0,  %12, %18\n\t"
        "global_load_dwordx4 %1,  %13, %18\n\t"
        "global_load_dwordx4 %2,  %14, %18\n\t"
        "global_load_dwordx4 %3,  %15, %18\n\t"
        "global_load_dwordx4 %4,  %16, %18\n\t"
        "global_load_dwordx4 %5,  %17, %18\n\t"
        "global_load_dwordx4 %6,  %12, %19\n\t"
        "global_load_dwordx4 %7,  %13, %19\n\t"
        "global_load_dwordx4 %8,  %14, %19\n\t"
        "global_load_dwordx4 %9,  %15, %19\n\t"
        "global_load_dwordx4 %10, %16, %19\n\t"
        "global_load_dwordx4 %11, %17, %19"
        : "=&v"(a0), "=&v"(a1), "=&v"(a2), "=&v"(a3), "=&v"(a4), "=&v"(a5),
          "=&v"(b0), "=&v"(b1), "=&v"(b2), "=&v"(b3), "=&v"(b4), "=&v"(b5)
        : "v"(v0), "v"(v1), "v"(v2), "v"(v3), "v"(v4), "v"(v5),
          "s"(pb0), "s"(tb0));
    asm volatile(
        "global_load_dwordx4 %0,  %12, %18\n\t"
        "global_load_dwordx4 %1,  %13, %18\n\t"
        "global_load_dwordx4 %2,  %14, %18\n\t"
        "global_load_dwordx4 %3,  %15, %18\n\t"
        "global_load_dwordx4 %4,  %16, %18\n\t"
        "global_load_dwordx4 %5,  %17, %18\n\t"
        "global_load_dwordx4 %6,  %12, %19\n\t"
        "global_load_dwordx4 %7,  %13, %19\n\t"
        "global_load_dwordx4 %8,  %14, %19\n\t"
        "global_load_dwordx4 %9,  %15, %19\n\t"
        "global_load_dwordx4 %10, %16, %19\n\t"
        "global_load_dwordx4 %11, %17, %19"
        : "=&v"(c0), "=&v"(c1), "=&v"(c2), "=&v"(c3), "=&v"(c4), "=&v"(c5),
          "=&v"(d0), "=&v"(d1), "=&v"(d2), "=&v"(d3), "=&v"(d4), "=&v"(d5)
        : "v"(v0), "v"(v1), "v"(v2), "v"(v3), "v"(v4), "v"(v5),
          "s"(pb1), "s"(tb1));

    float sum0 = 0.0f, sum1 = 0.0f;
    float bv0 = -1.0f, bv1 = -1.0f;      // |t| >= 0, always beaten
    int   bi0 = INT_MAX, bi1 = INT_MAX;

    // Indices strictly increase within a thread -> '>' keeps first occurrence.
#define CONSUME(PP, TT, K, SUM, BV, BI)                                        \
    do {                                                                       \
        const int base = (tid + (K) * 256) * 4;                                \
        SUM += fabsf(PP.x - TT.x) + fabsf(PP.y - TT.y) +                       \
               fabsf(PP.z - TT.z) + fabsf(PP.w - TT.w);                        \
        float a_;                                                              \
        a_ = fabsf(TT.x); if (a_ > BV) { BV = a_; BI = base;     }             \
        a_ = fabsf(TT.y); if (a_ > BV) { BV = a_; BI = base + 1; }             \
        a_ = fabsf(TT.z); if (a_ > BV) { BV = a_; BI = base + 2; }             \
        a_ = fabsf(TT.w); if (a_ > BV) { BV = a_; BI = base + 3; }             \
    } while (0)

    // row0 consume: row1's 12 loads may remain outstanding
    asm volatile("s_waitcnt vmcnt(12)" ::: "memory");
    __builtin_amdgcn_sched_barrier(0);
    CONSUME(a0, b0, 0, sum0, bv0, bi0);
    CONSUME(a1, b1, 1, sum0, bv0, bi0);
    CONSUME(a2, b2, 2, sum0, bv0, bi0);
    CONSUME(a3, b3, 3, sum0, bv0, bi0);
    CONSUME(a4, b4, 4, sum0, bv0, bi0);
    if (has6) CONSUME(a5, b5, 5, sum0, bv0, bi0);

    asm volatile("s_waitcnt vmcnt(0)" ::: "memory");
    __builtin_amdgcn_sched_barrier(0);
    CONSUME(c0, d0, 0, sum1, bv1, bi1);
    CONSUME(c1, d1, 1, sum1, bv1, bi1);
    CONSUME(c2, d2, 2, sum1, bv1, bi1);
    CONSUME(c3, d3, 3, sum1, bv1, bi1);
    CONSUME(c4, d4, 4, sum1, bv1, bi1);
    if (has6) CONSUME(c5, d5, 5, sum1, bv1, bi1);
#undef CONSUME

    // ---- interleaved wave reduce (both rows): sum + argmax (tie -> min idx)
    #pragma unroll
    for (int o = 32; o > 0; o >>= 1) {
        sum0 += __shfl_xor(sum0, o);
        sum1 += __shfl_xor(sum1, o);
        const float ov0 = __shfl_xor(bv0, o);
        const int   oi0 = __shfl_xor(bi0, o);
        const float ov1 = __shfl_xor(bv1, o);
        const int   oi1 = __shfl_xor(bi1, o);
        if (ov0 > bv0 || (ov0 == bv0 && oi0 < bi0)) { bv0 = ov0; bi0 = oi0; }
        if (ov1 > bv1 || (ov1 == bv1 && oi1 < bi1)) { bv1 = ov1; bi1 = oi1; }
    }

    __shared__ float s_sum[2][4];
    __shared__ float s_val[2][4];
    __shared__ int   s_idx[2][4];
    if (lane == 0) {
        s_sum[0][wave] = sum0; s_val[0][wave] = bv0; s_idx[0][wave] = bi0;
        s_sum[1][wave] = sum1; s_val[1][wave] = bv1; s_idx[1][wave] = bi1;
    }
    __syncthreads();

    // ---- wave 0 -> row0 pick, wave 1 -> row1 pick (concurrent)
    if (wave < 2) {
        const int r = wave;
        const int row = row0 + r;
        float bs = 0.0f, bv = -1.0f;
        int   bi = INT_MAX;
        #pragma unroll
        for (int w = 0; w < 4; ++w) {
            bs += s_sum[r][w];
            if (s_val[r][w] > bv || (s_val[r][w] == bv && s_idx[r][w] < bi)) {
                bv = s_val[r][w]; bi = s_idx[r][w];
            }
        }

        const int c   = bi;
        const int s   = max(0, c - PICK_WIN);
        const int e   = min(T_LEN, c + PICK_WIN);
        const int len = e - s;

        float ap = -INFINITY, at = -INFINITY;
        const float posf = (float)(s + lane);
        if (lane < len) {
            const size_t idx = (size_t)row * T_LEN + s + lane;
            ap = BETA * fabsf(pred[idx]);     // L2-hot: just streamed
            at = BETA * fabsf(target[idx]);
        }

        float mp = ap, mt = at;
        #pragma unroll
        for (int o = 32; o > 0; o >>= 1) {
            mp = fmaxf(mp, __shfl_xor(mp, o));
            mt = fmaxf(mt, __shfl_xor(mt, o));
        }

        float wp = 0.0f, wt = 0.0f, wpp = 0.0f, wtp = 0.0f;
        if (lane < len) {
            wp  = expf(ap - mp);
            wt  = expf(at - mt);
            wpp = wp * posf;
            wtp = wt * posf;
        }
        #pragma unroll
        for (int o = 32; o > 0; o >>= 1) {
            wp  += __shfl_xor(wp,  o);
            wt  += __shfl_xor(wt,  o);
            wpp += __shfl_xor(wpp, o);
            wtp += __shfl_xor(wtp, o);
        }

        if (lane == 0) {
            row_l1[row]   = bs;
            row_pick[row] = fabsf(wpp / wp - wtp / wt);
        }
    }
}

// ---------------------------------------------------------------------------
// K2: deterministic final reduce + combine (1 block; float4 loads).
// ---------------------------------------------------------------------------
__global__ __launch_bounds__(256) void finalize(const float* __restrict__ row_l1,
                                                const float* __restrict__ row_pick,
                                                float* __restrict__ out) {
    const int tid  = threadIdx.x;
    const int wave = tid >> 6;
    const int lane = tid & 63;
    const f4* l4 = (const f4*)row_l1;
    const f4* p4 = (const f4*)row_pick;

    float a = 0.0f, b = 0.0f;
    #pragma unroll
    for (int k = 0; k < 4; ++k) {
        const f4 x = l4[tid + k * 256];
        const f4 y = p4[tid + k * 256];
        a += x.x + x.y + x.z + x.w;
        b += y.x + y.y + y.z + y.w;
    }
    #pragma unroll
    for (int o = 32; o > 0; o >>= 1) {
        a += __shfl_xor(a, o);
        b += __shfl_xor(b, o);
    }
    __shared__ float f1[4], f2[4];
    if (lane == 0) { f1[wave] = a; f2[wave] = b; }
    __syncthreads();
    if (tid == 0) {
        const float ta = f1[0] + f1[1] + f1[2] + f1[3];
        const float tb = f2[0] + f2[1] + f2[2] + f2[3];
        const float loss = ta / (float)((long long)B_ROWS * (long long)T_LEN);
        const float pick = (tb / (float)B_ROWS) / (float)T_LEN;
        out[0] = loss + 0.1f * pick;
    }
}

extern "C" void kernel_launch(void* const* d_in, const int* in_sizes, int n_in,
                              void* d_out, int out_size, void* d_ws, size_t ws_size,
                              hipStream_t stream) {
    const float* pred   = (const float*)d_in[0];
    const float* target = (const float*)d_in[1];
    float* out = (float*)d_out;

    // workspace layout: [row_l1: 4096 f32][row_pick: 4096 f32]
    float* row_l1   = (float*)d_ws;
    float* row_pick = row_l1 + B_ROWS;

    row_pass1<<<B_ROWS / 2, 256, 0, stream>>>(pred, target, row_l1, row_pick);
    finalize<<<1, 256, 0, stream>>>(row_l1, row_pick, out);
}